// Round 2
// baseline (3719.103 us; speedup 1.0000x reference)
//
#include <hip/hip_runtime.h>
#include <hip/hip_bf16.h>

#define HW 9216          // 96*96
#define NPC 18432        // per-channel element count = B*H*W
#define NELEM 1179648    // 2*64*96*96

// ---------------------------------------------------------------------------
// Dtype detection: read first 4096 elements of w1 as bf16 words. Real bf16
// weights are |w| <= ~0.7; if the underlying data is f32, the interleaved
// mantissa-low words are ~uniform 16-bit -> magnitudes >= 100 show up with
// ~50% probability per word. flag=1 => inputs/outputs are f32.
// ---------------------------------------------------------------------------
__global__ void detect_kernel(const unsigned short* __restrict__ w1u,
                              int* __restrict__ flag) {
    int t = threadIdx.x;  // 64
    int bad = 0;
    for (int i = t; i < 4096; i += 64) {
        unsigned short u = (unsigned short)(w1u[i] & 0x7FFF);
        if (u >= 0x42C8) bad = 1;   // bf16 |v| >= 100.0 or NaN/Inf
    }
    unsigned long long any = __ballot(bad != 0);
    if (t == 0) *flag = (any != 0ULL) ? 1 : 0;
}

__device__ __forceinline__ float load_in(const void* p, int idx, int is32) {
    return is32 ? ((const float*)p)[idx]
                : __bfloat162float(((const __hip_bfloat16*)p)[idx]);
}

// ---------------------------------------------------------------------------
// Weight transpose: w[o][i][dy][dx][l][m] -> wT[o][i*9+k][m][l] (f32)
// so that lane m reads its 8 l-values as two contiguous float4s.
// ---------------------------------------------------------------------------
__global__ void wtrans_kernel(const void* __restrict__ w1,
                              const void* __restrict__ w2,
                              float* __restrict__ wT1, float* __restrict__ wT2,
                              const int* __restrict__ flag) {
    int is32 = *flag;
    int t = blockIdx.x * 256 + threadIdx.x;
    if (t >= 2 * 36864) return;
    const void* w = (t < 36864) ? w1 : w2;
    float* wT = (t < 36864) ? wT1 : wT2;
    int e = t % 36864;
    // e = ((o*8+i)*9 + k)*64 + m*8 + l
    int l  = e & 7;
    int m  = (e >> 3) & 7;
    int k  = (e >> 6) % 9;
    int oi = e / 576;
    int dy = k / 3, dx = k % 3;
    int src = (((oi * 3 + dy) * 3 + dx) * 8 + l) * 8 + m;
    wT[e] = load_in(w, src, is32);
}

// ---------------------------------------------------------------------------
// Fused capsule conv + dynamic routing.
// Block = 256 threads = 32 groups of 8 lanes; group g -> (px = g>>3, o = g&7),
// lane = m. Each lane holds priors[72] (fully unrolled => registers).
// ---------------------------------------------------------------------------
__launch_bounds__(256)
__global__ void caps_kernel(const void* __restrict__ xin,   // layer1 input
                            const float* __restrict__ yin,  // layer2 input
                            const float* __restrict__ scale,
                            const float* __restrict__ shift,
                            const float* __restrict__ wT,
                            float* __restrict__ yout,
                            const int* __restrict__ flag,
                            int layer1) {
    __shared__ float lds_in[8 * 3 * 6 * 8];   // [i][dy][col][l]
    __shared__ float lds_n1[32 * 73];         // [group][j], stride 73 conflict-free

    const int is32 = *flag;
    const int b  = blockIdx.z;
    const int y  = blockIdx.y;
    const int x0 = blockIdx.x * 4;
    const int tid = threadIdx.x;

    // ---- stage input patch (rows y-1..y+1, cols x0-1..x0+4, 64 channels) ----
    for (int e = tid; e < 1152; e += 256) {
        int l = e & 7;
        int q = e >> 3;          // 0..143
        int col = q % 6;
        int r = q / 6;           // 0..23
        int dy = r % 3;
        int i  = r / 3;
        int c  = i * 8 + l;
        int yy = y - 1 + dy, xx = x0 - 1 + col;
        float v = 0.f;
        if (yy >= 0 && yy < 96 && xx >= 0 && xx < 96) {
            int gidx = ((b * 64 + c) * 96 + yy) * 96 + xx;
            if (layer1) v = load_in(xin, gidx, is32);
            else        v = yin[gidx] * scale[c] + shift[c];
        }
        lds_in[e] = v;
    }
    __syncthreads();

    const int m  = tid & 7;
    const int g  = tid >> 3;
    const int o  = g & 7;
    const int px = g >> 3;       // 0..3

    // ---- priors[j] = sum_l p[i,k,l] * w[o,i,k,l,m] ----
    float priors[72];
    const float* wbase = wT + o * 4608 + m * 8;   // + j*64 + l
    #pragma unroll
    for (int j = 0; j < 72; ++j) {
        const int i = j / 9, k = j % 9;
        const int dy = k / 3, dx = k % 3;
        const float4* pv = (const float4*)&lds_in[((i * 3 + dy) * 6 + (px + dx)) * 8];
        const float4* wv = (const float4*)(wbase + j * 64);
        float4 p0 = pv[0], p1 = pv[1];
        float4 w0 = wv[0], w1 = wv[1];
        float acc = p0.x * w0.x;
        acc = fmaf(p0.y, w0.y, acc);
        acc = fmaf(p0.z, w0.z, acc);
        acc = fmaf(p0.w, w0.w, acc);
        acc = fmaf(p1.x, w1.x, acc);
        acc = fmaf(p1.y, w1.y, acc);
        acc = fmaf(p1.z, w1.z, acc);
        acc = fmaf(p1.w, w1.w, acc);
        priors[j] = acc;
    }

    // ---- n1[j] = sum_m priors[j][m]^2 (8-lane butterfly), park in LDS ----
    float* n1 = &lds_n1[g * 73];
    #pragma unroll
    for (int j = 0; j < 72; ++j) {
        float t = priors[j] * priors[j];
        t += __shfl_xor(t, 1);
        t += __shfl_xor(t, 2);
        t += __shfl_xor(t, 4);
        if (m == 0) n1[j] = t;
    }
    __syncthreads();   // make n1 visible (belt & suspenders vs DS reordering)

    // ---- out init: mean over j (local to lane m) ----
    float outm = 0.f;
    #pragma unroll
    for (int j = 0; j < 72; ++j) outm += priors[j];
    outm *= (1.f / 72.f);

    // ---- 3 routing iterations ----
    // logits = dot/max(n1+n2-dot,eps) is bounded in [-1,1] => exp safe.
    for (int it = 0; it < 3; ++it) {
        float t = outm * outm;
        t += __shfl_xor(t, 1);
        t += __shfl_xor(t, 2);
        t += __shfl_xor(t, 4);
        const float n2 = t;
        float sumexp = 0.f, acc = 0.f;
        #pragma unroll
        for (int j = 0; j < 72; ++j) {
            float d = priors[j] * outm;
            d += __shfl_xor(d, 1);
            d += __shfl_xor(d, 2);
            d += __shfl_xor(d, 4);
            float denom = fmaxf(n1[j] + n2 - d, 1e-8f);
            float lg = d * __builtin_amdgcn_rcpf(denom);
            lg = fminf(fmaxf(lg, -4.f), 4.f);   // math says |lg|<=1; clamp anyway
            float e = __expf(lg);
            sumexp += e;
            acc = fmaf(e, priors[j], acc);
        }
        outm = acc * __builtin_amdgcn_rcpf(sumexp);
    }

    // ---- store y[b][o*8+m][y][x] ----
    yout[((b * 64 + (o * 8 + m)) * 96 + y) * 96 + (x0 + px)] = outm;
}

// ---------------------------------------------------------------------------
// Per-channel sum / sumsq (one block per channel, deterministic, no atomics).
// ---------------------------------------------------------------------------
__global__ void chanstats_kernel(const float* __restrict__ yv,
                                 float* __restrict__ sums, float* __restrict__ sumsqs) {
    const int c = blockIdx.x;     // 0..63
    const int tid = threadIdx.x;  // 256
    float s = 0.f, ss = 0.f;
    for (int e = tid; e < NPC; e += 256) {
        int bb = e / HW, p = e % HW;
        float v = yv[(bb * 64 + c) * HW + p];
        s += v;
        ss = fmaf(v, v, ss);
    }
    #pragma unroll
    for (int d = 1; d < 64; d <<= 1) {
        s  += __shfl_xor(s, d);
        ss += __shfl_xor(ss, d);
    }
    __shared__ float ls[4], lss[4];
    int w = tid >> 6;
    if ((tid & 63) == 0) { ls[w] = s; lss[w] = ss; }
    __syncthreads();
    if (tid == 0) {
        sums[c]   = ls[0] + ls[1] + ls[2] + ls[3];
        sumsqs[c] = lss[0] + lss[1] + lss[2] + lss[3];
    }
}

// ---------------------------------------------------------------------------
// Fold BN into per-channel scale/shift.
// ---------------------------------------------------------------------------
__global__ void bnparams_kernel(const float* __restrict__ sums, const float* __restrict__ sumsqs,
                                const void* __restrict__ gamma,
                                const void* __restrict__ beta,
                                float* __restrict__ sc, float* __restrict__ sh,
                                const int* __restrict__ flag) {
    int is32 = *flag;
    int c = threadIdx.x;  // 64
    float mean = sums[c] * (1.f / (float)NPC);
    float var  = sumsqs[c] * (1.f / (float)NPC) - mean * mean;
    var = fmaxf(var, 0.f);
    float inv  = rsqrtf(var + 1e-5f);
    float s = load_in(gamma, c, is32) * inv;
    sc[c] = s;
    sh[c] = load_in(beta, c, is32) - mean * s;
}

// ---------------------------------------------------------------------------
// out = x + bn2(y2), stored in the detected output dtype.
// ---------------------------------------------------------------------------
__global__ void final_kernel(const void* __restrict__ xin,
                             const float* __restrict__ y2,
                             const float* __restrict__ sc, const float* __restrict__ sh,
                             void* __restrict__ outp,
                             const int* __restrict__ flag) {
    int is32 = *flag;
    int idx = blockIdx.x * 256 + threadIdx.x;
    if (idx >= NELEM) return;
    int c = (idx / HW) & 63;
    float v = load_in(xin, idx, is32) + y2[idx] * sc[c] + sh[c];
    if (is32) ((float*)outp)[idx] = v;
    else      ((__hip_bfloat16*)outp)[idx] = __float2bfloat16(v);
}

// ---------------------------------------------------------------------------
extern "C" void kernel_launch(void* const* d_in, const int* in_sizes, int n_in,
                              void* d_out, int out_size, void* d_ws, size_t ws_size,
                              hipStream_t stream) {
    const void* x  = d_in[0];
    const void* w1 = d_in[1];
    const void* g1 = d_in[2];
    const void* b1 = d_in[3];
    const void* w2 = d_in[4];
    const void* g2 = d_in[5];
    const void* b2 = d_in[6];

    float* ws   = (float*)d_ws;
    float* y1   = ws;                    // 1179648
    float* y2   = y1 + NELEM;            // 1179648
    float* wT1  = y2 + NELEM;            // 36864
    float* wT2  = wT1 + 36864;           // 36864
    float* stats = wT2 + 36864;
    float* sum1 = stats, *sumsq1 = stats + 64;
    float* sum2 = stats + 128, *sumsq2 = stats + 192;
    float* sc1  = stats + 256, *sh1 = stats + 320;
    float* sc2  = stats + 384, *sh2 = stats + 448;
    int*  flag  = (int*)(stats + 512);

    detect_kernel<<<1, 64, 0, stream>>>((const unsigned short*)w1, flag);
    wtrans_kernel<<<(2 * 36864 + 255) / 256, 256, 0, stream>>>(w1, w2, wT1, wT2, flag);

    dim3 grid(24, 96, 2);   // x-tiles of 4, rows, batch
    caps_kernel<<<grid, 256, 0, stream>>>(x, nullptr, nullptr, nullptr, wT1, y1, flag, 1);
    chanstats_kernel<<<64, 256, 0, stream>>>(y1, sum1, sumsq1);
    bnparams_kernel<<<1, 64, 0, stream>>>(sum1, sumsq1, g1, b1, sc1, sh1, flag);

    caps_kernel<<<grid, 256, 0, stream>>>(nullptr, y1, sc1, sh1, wT2, y2, flag, 0);
    chanstats_kernel<<<64, 256, 0, stream>>>(y2, sum2, sumsq2);
    bnparams_kernel<<<1, 64, 0, stream>>>(sum2, sumsq2, g2, b2, sc2, sh2, flag);

    final_kernel<<<(NELEM + 255) / 256, 256, 0, stream>>>(x, y2, sc2, sh2, d_out, flag);
}

// Round 3
// 749.732 us; speedup vs baseline: 4.9606x; 4.9606x over previous
//
#include <hip/hip_runtime.h>
#include <hip/hip_bf16.h>

#define HW 9216          // 96*96
#define NPOS 18432       // B*H*W positions
#define NPC 18432        // per-channel element count for BN
#define NELEM 1179648    // 2*64*96*96

// ---------------------------------------------------------------------------
// Dtype detection (bf16 vs f32 inputs), as validated in R2.
// ---------------------------------------------------------------------------
__global__ void detect_kernel(const unsigned short* __restrict__ w1u,
                              int* __restrict__ flag) {
    int t = threadIdx.x;  // 64
    int bad = 0;
    for (int i = t; i < 4096; i += 64) {
        unsigned short u = (unsigned short)(w1u[i] & 0x7FFF);
        if (u >= 0x42C8) bad = 1;   // bf16 |v| >= 100.0 or NaN/Inf
    }
    unsigned long long any = __ballot(bad != 0);
    if (t == 0) *flag = (any != 0ULL) ? 1 : 0;
}

__device__ __forceinline__ float load_in(const void* p, int idx, int is32) {
    return is32 ? ((const float*)p)[idx]
                : __bfloat162float(((const __hip_bfloat16*)p)[idx]);
}

// ---------------------------------------------------------------------------
// Weight transpose: w[o][i][dy][dx][l][m] -> wT[o][j=i*9+k][m][l] (f32)
// ---------------------------------------------------------------------------
__global__ void wtrans_kernel(const void* __restrict__ w1,
                              const void* __restrict__ w2,
                              float* __restrict__ wT1, float* __restrict__ wT2,
                              const int* __restrict__ flag) {
    int is32 = *flag;
    int t = blockIdx.x * 256 + threadIdx.x;
    if (t >= 2 * 36864) return;
    const void* w = (t < 36864) ? w1 : w2;
    float* wT = (t < 36864) ? wT1 : wT2;
    int e = t % 36864;
    // e = ((o*8+i)*9 + k)*64 + m*8 + l
    int l  = e & 7;
    int m  = (e >> 3) & 7;
    int k  = (e >> 6) % 9;
    int oi = e / 576;
    int dy = k / 3, dx = k % 3;
    int src = (((oi * 3 + dy) * 3 + dx) * 8 + l) * 8 + m;
    wT[e] = load_in(w, src, is32);
}

// ---------------------------------------------------------------------------
// Input transpose: x [b][c][96][96] (bf16/f32) -> xt [b][y][x][c] (f32).
// Tiled 64c x 32x through LDS; both phases coalesced.
// ---------------------------------------------------------------------------
__global__ void xtrans_kernel(const void* __restrict__ x, float* __restrict__ xt,
                              const int* __restrict__ flag) {
    __shared__ float tile[64 * 33];
    int is32 = *flag;
    int x0 = blockIdx.x * 32, y = blockIdx.y, b = blockIdx.z;
    for (int e = threadIdx.x; e < 2048; e += 256) {
        int xl = e & 31, c = e >> 5;
        tile[c * 33 + xl] = load_in(x, ((b * 64 + c) * 96 + y) * 96 + x0 + xl, is32);
    }
    __syncthreads();
    for (int f = threadIdx.x; f < 2048; f += 256) {
        int c = f & 63, xl = f >> 6;
        xt[((b * 96 + y) * 96 + x0 + xl) * 64 + c] = tile[c * 33 + xl];
    }
}

// ---------------------------------------------------------------------------
// Fused capsule conv + routing. Block = 512 = 8 waves; wave = o; each wave
// handles 2 x-positions. Lane = (jj=i, m): pr[2][9] priors in registers.
// ---------------------------------------------------------------------------
__launch_bounds__(512)
__global__ void caps_kernel(const float* __restrict__ in,     // [b][y][x][64]
                            const float* __restrict__ scale,  // layer2 BN fold
                            const float* __restrict__ shift,
                            const float* __restrict__ wT,
                            float* __restrict__ yout,         // [b][y][x][64]
                            int layer1) {
    __shared__ float lp[768];   // [i][dy][col 0..3][l], 3 rows x 4 cols x 64 ch

    const int x0 = blockIdx.x * 2;
    const int y  = blockIdx.y;
    const int b  = blockIdx.z;
    const int tid = threadIdx.x;

    // ---- stage patch: rows y-1..y+1, cols x0-1..x0+2, 64 channels ----
    for (int e = tid; e < 768; e += 512) {
        int l = e & 7;
        int q = e >> 3;          // 0..95
        int col = q & 3;
        int r = q >> 2;          // 0..23
        int dy = r % 3;
        int i  = r / 3;
        int c  = i * 8 + l;
        int yy = y - 1 + dy, xx = x0 - 1 + col;
        float v = 0.f;
        if (yy >= 0 && yy < 96 && xx >= 0 && xx < 96) {
            v = in[((b * 96 + yy) * 96 + xx) * 64 + c];
            if (!layer1) v = v * scale[c] + shift[c];
        }
        lp[e] = v;
    }
    __syncthreads();

    const int o    = tid >> 6;        // wave index
    const int lane = tid & 63;
    const int m    = lane & 7;
    const int jj   = lane >> 3;       // input capsule i

    // ---- priors: pr[px][t], t = k = dy*3+dx ----
    float pr0[9], pr1[9];
    const float* wb = wT + o * 4608 + jj * 576 + m * 8;
    #pragma unroll
    for (int t = 0; t < 9; ++t) {
        const int dy = t / 3, dx = t % 3;
        float4 w0 = *(const float4*)(wb + t * 64);
        float4 w1 = *(const float4*)(wb + t * 64 + 4);
        #pragma unroll
        for (int px = 0; px < 2; ++px) {
            const float* pb = &lp[((jj * 3 + dy) * 4 + (dx + px)) * 8];
            float4 p0 = *(const float4*)pb;
            float4 p1 = *(const float4*)(pb + 4);
            float acc = p0.x * w0.x;
            acc = fmaf(p0.y, w0.y, acc);
            acc = fmaf(p0.z, w0.z, acc);
            acc = fmaf(p0.w, w0.w, acc);
            acc = fmaf(p1.x, w1.x, acc);
            acc = fmaf(p1.y, w1.y, acc);
            acc = fmaf(p1.z, w1.z, acc);
            acc = fmaf(p1.w, w1.w, acc);
            if (px == 0) pr0[t] = acc; else pr1[t] = acc;
        }
    }

    // ---- routing for both positions ----
    #pragma unroll
    for (int px = 0; px < 2; ++px) {
        float* pr = (px == 0) ? pr0 : pr1;

        float n1[9];
        #pragma unroll
        for (int t = 0; t < 9; ++t) {
            float s = pr[t] * pr[t];
            s += __shfl_xor(s, 1);
            s += __shfl_xor(s, 2);
            s += __shfl_xor(s, 4);
            n1[t] = s;               // per-j ||p||^2, replicated over m
        }

        float om = 0.f;              // out[m], init = mean over all 72 j
        #pragma unroll
        for (int t = 0; t < 9; ++t) om += pr[t];
        om += __shfl_xor(om, 8);
        om += __shfl_xor(om, 16);
        om += __shfl_xor(om, 32);
        om *= (1.f / 72.f);

        for (int it = 0; it < 3; ++it) {
            float n2 = om * om;
            n2 += __shfl_xor(n2, 1);
            n2 += __shfl_xor(n2, 2);
            n2 += __shfl_xor(n2, 4);
            float se = 0.f, acc = 0.f;
            #pragma unroll
            for (int t = 0; t < 9; ++t) {
                float d = pr[t] * om;
                d += __shfl_xor(d, 1);
                d += __shfl_xor(d, 2);
                d += __shfl_xor(d, 4);
                float denom = fmaxf(n1[t] + n2 - d, 1e-8f);
                float e = __expf(d * __builtin_amdgcn_rcpf(denom));
                se  += e;
                acc  = fmaf(e, pr[t], acc);
            }
            se  += __shfl_xor(se, 8);
            se  += __shfl_xor(se, 16);
            se  += __shfl_xor(se, 32);
            acc += __shfl_xor(acc, 8);
            acc += __shfl_xor(acc, 16);
            acc += __shfl_xor(acc, 32);
            om = acc * __builtin_amdgcn_rcpf(se);
        }

        if (jj == 0)
            yout[((b * 96 + y) * 96 + (x0 + px)) * 64 + o * 8 + m] = om;
    }
}

// ---------------------------------------------------------------------------
// BN stats stage 1: per-block partial sum/sumsq over a contiguous pos range.
// yt is [pos][c]; fully coalesced. Grid 64 blocks x 256 threads.
// ---------------------------------------------------------------------------
__global__ void stats_kernel(const float* __restrict__ yt,
                             float* __restrict__ pS, float* __restrict__ pSS) {
    const int c = threadIdx.x & 63, sub = threadIdx.x >> 6;
    const int base = blockIdx.x * 288;
    float s = 0.f, ss = 0.f;
    for (int r = 0; r < 72; ++r) {
        float v = yt[(base + r * 4 + sub) * 64 + c];
        s += v;
        ss = fmaf(v, v, ss);
    }
    __shared__ float ls[4][64], lss[4][64];
    ls[sub][c] = s;
    lss[sub][c] = ss;
    __syncthreads();
    if (threadIdx.x < 64) {
        int cc = threadIdx.x;
        pS[blockIdx.x * 64 + cc]  = ls[0][cc] + ls[1][cc] + ls[2][cc] + ls[3][cc];
        pSS[blockIdx.x * 64 + cc] = lss[0][cc] + lss[1][cc] + lss[2][cc] + lss[3][cc];
    }
}

// ---------------------------------------------------------------------------
// BN stats stage 2: reduce 64 partials per channel, fold gamma/beta.
// ---------------------------------------------------------------------------
__global__ void bnparams_kernel(const float* __restrict__ pS, const float* __restrict__ pSS,
                                const void* __restrict__ gamma,
                                const void* __restrict__ beta,
                                float* __restrict__ sc, float* __restrict__ sh,
                                const int* __restrict__ flag) {
    int is32 = *flag;
    int c = threadIdx.x;  // 64
    float s = 0.f, ss = 0.f;
    for (int k = 0; k < 64; ++k) { s += pS[k * 64 + c]; ss += pSS[k * 64 + c]; }
    float mean = s * (1.f / (float)NPC);
    float var  = fmaxf(ss * (1.f / (float)NPC) - mean * mean, 0.f);
    float inv  = rsqrtf(var + 1e-5f);
    float g = load_in(gamma, c, is32) * inv;
    sc[c] = g;
    sh[c] = load_in(beta, c, is32) - mean * g;
}

// ---------------------------------------------------------------------------
// Final: out[b][c][y][x] = x + bn2(y2), tiled transpose from [pos][c].
// ---------------------------------------------------------------------------
__global__ void final_kernel(const void* __restrict__ xin,
                             const float* __restrict__ yt2,
                             const float* __restrict__ sc, const float* __restrict__ sh,
                             void* __restrict__ outp,
                             const int* __restrict__ flag) {
    __shared__ float tile[64 * 33];
    int is32 = *flag;
    int x0 = blockIdx.x * 32, y = blockIdx.y, b = blockIdx.z;
    for (int e = threadIdx.x; e < 2048; e += 256) {
        int c = e & 63, xl = e >> 6;
        float v = yt2[((b * 96 + y) * 96 + x0 + xl) * 64 + c];
        tile[c * 33 + xl] = v * sc[c] + sh[c];
    }
    __syncthreads();
    for (int f = threadIdx.x; f < 2048; f += 256) {
        int xl = f & 31, c = f >> 5;
        int idx = ((b * 64 + c) * 96 + y) * 96 + x0 + xl;
        float v = load_in(xin, idx, is32) + tile[c * 33 + xl];
        if (is32) ((float*)outp)[idx] = v;
        else      ((__hip_bfloat16*)outp)[idx] = __float2bfloat16(v);
    }
}

// ---------------------------------------------------------------------------
extern "C" void kernel_launch(void* const* d_in, const int* in_sizes, int n_in,
                              void* d_out, int out_size, void* d_ws, size_t ws_size,
                              hipStream_t stream) {
    const void* x  = d_in[0];
    const void* w1 = d_in[1];
    const void* g1 = d_in[2];
    const void* b1 = d_in[3];
    const void* w2 = d_in[4];
    const void* g2 = d_in[5];
    const void* b2 = d_in[6];

    float* ws   = (float*)d_ws;
    float* bufA = ws;                  // xt (layer1 input) / yt2 (alias; xt dead by caps2)
    float* bufB = bufA + NELEM;        // yt1
    float* wT1  = bufB + NELEM;        // 36864
    float* wT2  = wT1 + 36864;         // 36864
    float* pS1  = wT2 + 36864;         // 4096
    float* pSS1 = pS1 + 4096;
    float* pS2  = pSS1 + 4096;
    float* pSS2 = pS2 + 4096;
    float* sc1  = pSS2 + 4096;
    float* sh1  = sc1 + 64;
    float* sc2  = sh1 + 64;
    float* sh2  = sc2 + 64;
    int*  flag  = (int*)(sh2 + 64);

    detect_kernel<<<1, 64, 0, stream>>>((const unsigned short*)w1, flag);
    wtrans_kernel<<<288, 256, 0, stream>>>(w1, w2, wT1, wT2, flag);
    xtrans_kernel<<<dim3(3, 96, 2), 256, 0, stream>>>(x, bufA, flag);

    dim3 cgrid(48, 96, 2);
    caps_kernel<<<cgrid, 512, 0, stream>>>(bufA, sc1, sh1, wT1, bufB, 1);
    stats_kernel<<<64, 256, 0, stream>>>(bufB, pS1, pSS1);
    bnparams_kernel<<<1, 64, 0, stream>>>(pS1, pSS1, g1, b1, sc1, sh1, flag);

    caps_kernel<<<cgrid, 512, 0, stream>>>(bufB, sc1, sh1, wT2, bufA, 0);
    stats_kernel<<<64, 256, 0, stream>>>(bufA, pS2, pSS2);
    bnparams_kernel<<<1, 64, 0, stream>>>(pS2, pSS2, g2, b2, sc2, sh2, flag);

    final_kernel<<<dim3(3, 96, 2), 256, 0, stream>>>(x, bufA, sc2, sh2, d_out, flag);
}

// Round 4
// 566.541 us; speedup vs baseline: 6.5646x; 1.3233x over previous
//
#include <hip/hip_runtime.h>
#include <hip/hip_bf16.h>

#define HW 9216          // 96*96
#define NPC 18432        // per-channel element count for BN
#define NELEM 1179648    // 2*64*96*96

// ---------------------------------------------------------------------------
// DPP-based cross-lane add: x + lane_xor_pattern(x). VALU pipe, no DS.
//   xor1 : quad_perm [1,0,3,2]   = 0xB1
//   xor2 : quad_perm [2,3,0,1]   = 0x4E
//   xor4 : row_half_mirror       = 0x141 (valid once value is quad-uniform)
//   xor8 : row_ror:8             = 0x128 ((i±8)%16 == i^8)
// ---------------------------------------------------------------------------
template <int CTRL>
__device__ __forceinline__ float dpp_add(float x) {
    int y = __builtin_amdgcn_update_dpp(0, __float_as_int(x), CTRL, 0xF, 0xF, true);
    return x + __int_as_float(y);
}
// sum over the 8-lane m-group (lanes i, i^1, i^2, ..., i^7)
__device__ __forceinline__ float red_m(float x) {
    x = dpp_add<0xB1>(x);
    x = dpp_add<0x4E>(x);
    x = dpp_add<0x141>(x);
    return x;
}
// sum over jj = lane>>3 (xor 8, 16, 32)
__device__ __forceinline__ float red_j(float x) {
    x = dpp_add<0x128>(x);
    x += __shfl_xor(x, 16);
    x += __shfl_xor(x, 32);
    return x;
}

// ---------------------------------------------------------------------------
// Dtype detection (bf16 vs f32 inputs), validated in R2.
// ---------------------------------------------------------------------------
__global__ void detect_kernel(const unsigned short* __restrict__ w1u,
                              int* __restrict__ flag) {
    int t = threadIdx.x;  // 64
    int bad = 0;
    for (int i = t; i < 4096; i += 64) {
        unsigned short u = (unsigned short)(w1u[i] & 0x7FFF);
        if (u >= 0x42C8) bad = 1;   // bf16 |v| >= 100.0 or NaN/Inf
    }
    unsigned long long any = __ballot(bad != 0);
    if (t == 0) *flag = (any != 0ULL) ? 1 : 0;
}

__device__ __forceinline__ float load_in(const void* p, int idx, int is32) {
    return is32 ? ((const float*)p)[idx]
                : __bfloat162float(((const __hip_bfloat16*)p)[idx]);
}

// ---------------------------------------------------------------------------
// Weight transpose: w[o][i][dy][dx][l][m] -> wT[o][j=i*9+k][m][l] (f32)
// ---------------------------------------------------------------------------
__global__ void wtrans_kernel(const void* __restrict__ w1,
                              const void* __restrict__ w2,
                              float* __restrict__ wT1, float* __restrict__ wT2,
                              const int* __restrict__ flag) {
    int is32 = *flag;
    int t = blockIdx.x * 256 + threadIdx.x;
    if (t >= 2 * 36864) return;
    const void* w = (t < 36864) ? w1 : w2;
    float* wT = (t < 36864) ? wT1 : wT2;
    int e = t % 36864;
    // e = ((o*8+i)*9 + k)*64 + m*8 + l
    int l  = e & 7;
    int m  = (e >> 3) & 7;
    int k  = (e >> 6) % 9;
    int oi = e / 576;
    int dy = k / 3, dx = k % 3;
    int src = (((oi * 3 + dy) * 3 + dx) * 8 + l) * 8 + m;
    wT[e] = load_in(w, src, is32);
}

// ---------------------------------------------------------------------------
// Input transpose: x [b][c][96][96] -> xt [b][y][x][c] (f32).
// ---------------------------------------------------------------------------
__global__ void xtrans_kernel(const void* __restrict__ x, float* __restrict__ xt,
                              const int* __restrict__ flag) {
    __shared__ float tile[64 * 33];
    int is32 = *flag;
    int x0 = blockIdx.x * 32, y = blockIdx.y, b = blockIdx.z;
    for (int e = threadIdx.x; e < 2048; e += 256) {
        int xl = e & 31, c = e >> 5;
        tile[c * 33 + xl] = load_in(x, ((b * 64 + c) * 96 + y) * 96 + x0 + xl, is32);
    }
    __syncthreads();
    for (int f = threadIdx.x; f < 2048; f += 256) {
        int c = f & 63, xl = f >> 6;
        xt[((b * 96 + y) * 96 + x0 + xl) * 64 + c] = tile[c * 33 + xl];
    }
}

// ---------------------------------------------------------------------------
// Fused capsule conv + routing. Block = 512 = 8 waves; wave = o; each wave
// handles 2 x-positions. Lane = (jj=i, m): pr[2][9] priors in registers.
// LDS lp padded to stride 100/i -> conflict-free b128 reads (banks 4*jj).
// ---------------------------------------------------------------------------
__launch_bounds__(512)
__global__ void caps_kernel(const float* __restrict__ in,     // [b][y][x][64]
                            const float* __restrict__ scale,  // layer2 BN fold
                            const float* __restrict__ shift,
                            const float* __restrict__ wT,
                            float* __restrict__ yout,         // [b][y][x][64]
                            int layer1) {
    __shared__ float lp[800];   // [i]*100 + [dy*4+col]*8 + [l]

    const int x0 = blockIdx.x * 2;
    const int y  = blockIdx.y;
    const int b  = blockIdx.z;
    const int tid = threadIdx.x;

    // ---- stage patch: rows y-1..y+1, cols x0-1..x0+2, 64 channels ----
    for (int e = tid; e < 768; e += 512) {
        int l = e & 7;
        int q = e >> 3;          // 0..95
        int col = q & 3;
        int r = q >> 2;          // 0..23
        int dy = r % 3;
        int i  = r / 3;
        int c  = i * 8 + l;
        int yy = y - 1 + dy, xx = x0 - 1 + col;
        float v = 0.f;
        if (yy >= 0 && yy < 96 && xx >= 0 && xx < 96) {
            v = in[((b * 96 + yy) * 96 + xx) * 64 + c];
            if (!layer1) v = v * scale[c] + shift[c];
        }
        lp[i * 100 + (dy * 4 + col) * 8 + l] = v;
    }
    __syncthreads();

    const int o    = tid >> 6;        // wave index
    const int lane = tid & 63;
    const int m    = lane & 7;
    const int jj   = lane >> 3;       // input capsule i

    // ---- priors: pr[px][t], t = k = dy*3+dx ----
    float pr0[9], pr1[9];
    const float* wb = wT + o * 4608 + jj * 576 + m * 8;
    #pragma unroll
    for (int t = 0; t < 9; ++t) {
        const int dy = t / 3, dx = t % 3;
        float4 w0 = *(const float4*)(wb + t * 64);
        float4 w1 = *(const float4*)(wb + t * 64 + 4);
        #pragma unroll
        for (int px = 0; px < 2; ++px) {
            const float* pb = &lp[jj * 100 + (dy * 4 + dx + px) * 8];
            float4 p0 = *(const float4*)pb;
            float4 p1 = *(const float4*)(pb + 4);
            float acc = p0.x * w0.x;
            acc = fmaf(p0.y, w0.y, acc);
            acc = fmaf(p0.z, w0.z, acc);
            acc = fmaf(p0.w, w0.w, acc);
            acc = fmaf(p1.x, w1.x, acc);
            acc = fmaf(p1.y, w1.y, acc);
            acc = fmaf(p1.z, w1.z, acc);
            acc = fmaf(p1.w, w1.w, acc);
            if (px == 0) pr0[t] = acc; else pr1[t] = acc;
        }
    }

    // ---- routing for both positions ----
    #pragma unroll
    for (int px = 0; px < 2; ++px) {
        float* pr = (px == 0) ? pr0 : pr1;

        float n1[9];
        #pragma unroll
        for (int t = 0; t < 9; ++t)
            n1[t] = red_m(pr[t] * pr[t]);   // per-j ||p||^2, replicated over m

        float om = 0.f;                     // out[m], init = mean over all 72 j
        #pragma unroll
        for (int t = 0; t < 9; ++t) om += pr[t];
        om = red_j(om) * (1.f / 72.f);

        for (int it = 0; it < 3; ++it) {
            float n2 = red_m(om * om);
            float se = 0.f, acc = 0.f;
            #pragma unroll
            for (int t = 0; t < 9; ++t) {
                float d = red_m(pr[t] * om);
                float denom = fmaxf(n1[t] + n2 - d, 1e-8f);
                float e = __expf(d * __builtin_amdgcn_rcpf(denom));
                se  += e;
                acc  = fmaf(e, pr[t], acc);
            }
            se  = red_j(se);
            acc = red_j(acc);
            om = acc * __builtin_amdgcn_rcpf(se);
        }

        if (jj == 0)
            yout[((b * 96 + y) * 96 + (x0 + px)) * 64 + o * 8 + m] = om;
    }
}

// ---------------------------------------------------------------------------
// BN stats stage 1: per-block partial sum/sumsq, coalesced over [pos][c].
// ---------------------------------------------------------------------------
__global__ void stats_kernel(const float* __restrict__ yt,
                             float* __restrict__ pS, float* __restrict__ pSS) {
    const int c = threadIdx.x & 63, sub = threadIdx.x >> 6;
    const int base = blockIdx.x * 288;
    float s = 0.f, ss = 0.f;
    for (int r = 0; r < 72; ++r) {
        float v = yt[(base + r * 4 + sub) * 64 + c];
        s += v;
        ss = fmaf(v, v, ss);
    }
    __shared__ float ls[4][64], lss[4][64];
    ls[sub][c] = s;
    lss[sub][c] = ss;
    __syncthreads();
    if (threadIdx.x < 64) {
        int cc = threadIdx.x;
        pS[blockIdx.x * 64 + cc]  = ls[0][cc] + ls[1][cc] + ls[2][cc] + ls[3][cc];
        pSS[blockIdx.x * 64 + cc] = lss[0][cc] + lss[1][cc] + lss[2][cc] + lss[3][cc];
    }
}

// ---------------------------------------------------------------------------
// BN stats stage 2: reduce partials per channel, fold gamma/beta.
// ---------------------------------------------------------------------------
__global__ void bnparams_kernel(const float* __restrict__ pS, const float* __restrict__ pSS,
                                const void* __restrict__ gamma,
                                const void* __restrict__ beta,
                                float* __restrict__ sc, float* __restrict__ sh,
                                const int* __restrict__ flag) {
    int is32 = *flag;
    int c = threadIdx.x;  // 64
    float s = 0.f, ss = 0.f;
    for (int k = 0; k < 64; ++k) { s += pS[k * 64 + c]; ss += pSS[k * 64 + c]; }
    float mean = s * (1.f / (float)NPC);
    float var  = fmaxf(ss * (1.f / (float)NPC) - mean * mean, 0.f);
    float inv  = rsqrtf(var + 1e-5f);
    float g = load_in(gamma, c, is32) * inv;
    sc[c] = g;
    sh[c] = load_in(beta, c, is32) - mean * g;
}

// ---------------------------------------------------------------------------
// Final: out[b][c][y][x] = x + bn2(y2), tiled transpose from [pos][c].
// ---------------------------------------------------------------------------
__global__ void final_kernel(const void* __restrict__ xin,
                             const float* __restrict__ yt2,
                             const float* __restrict__ sc, const float* __restrict__ sh,
                             void* __restrict__ outp,
                             const int* __restrict__ flag) {
    __shared__ float tile[64 * 33];
    int is32 = *flag;
    int x0 = blockIdx.x * 32, y = blockIdx.y, b = blockIdx.z;
    for (int e = threadIdx.x; e < 2048; e += 256) {
        int c = e & 63, xl = e >> 6;
        float v = yt2[((b * 96 + y) * 96 + x0 + xl) * 64 + c];
        tile[c * 33 + xl] = v * sc[c] + sh[c];
    }
    __syncthreads();
    for (int f = threadIdx.x; f < 2048; f += 256) {
        int xl = f & 31, c = f >> 5;
        int idx = ((b * 64 + c) * 96 + y) * 96 + x0 + xl;
        float v = load_in(xin, idx, is32) + tile[c * 33 + xl];
        if (is32) ((float*)outp)[idx] = v;
        else      ((__hip_bfloat16*)outp)[idx] = __float2bfloat16(v);
    }
}

// ---------------------------------------------------------------------------
extern "C" void kernel_launch(void* const* d_in, const int* in_sizes, int n_in,
                              void* d_out, int out_size, void* d_ws, size_t ws_size,
                              hipStream_t stream) {
    const void* x  = d_in[0];
    const void* w1 = d_in[1];
    const void* g1 = d_in[2];
    const void* b1 = d_in[3];
    const void* w2 = d_in[4];
    const void* g2 = d_in[5];
    const void* b2 = d_in[6];

    float* ws   = (float*)d_ws;
    float* bufA = ws;                  // xt (layer1 input) / yt2 (alias; xt dead by caps2)
    float* bufB = bufA + NELEM;        // yt1
    float* wT1  = bufB + NELEM;        // 36864
    float* wT2  = wT1 + 36864;         // 36864
    float* pS1  = wT2 + 36864;         // 4096
    float* pSS1 = pS1 + 4096;
    float* pS2  = pSS1 + 4096;
    float* pSS2 = pS2 + 4096;
    float* sc1  = pSS2 + 4096;
    float* sh1  = sc1 + 64;
    float* sc2  = sh1 + 64;
    float* sh2  = sc2 + 64;
    int*  flag  = (int*)(sh2 + 64);

    detect_kernel<<<1, 64, 0, stream>>>((const unsigned short*)w1, flag);
    wtrans_kernel<<<288, 256, 0, stream>>>(w1, w2, wT1, wT2, flag);
    xtrans_kernel<<<dim3(3, 96, 2), 256, 0, stream>>>(x, bufA, flag);

    dim3 cgrid(48, 96, 2);
    caps_kernel<<<cgrid, 512, 0, stream>>>(bufA, sc1, sh1, wT1, bufB, 1);
    stats_kernel<<<64, 256, 0, stream>>>(bufB, pS1, pSS1);
    bnparams_kernel<<<1, 64, 0, stream>>>(pS1, pSS1, g1, b1, sc1, sh1, flag);

    caps_kernel<<<cgrid, 512, 0, stream>>>(bufB, sc1, sh1, wT2, bufA, 0);
    stats_kernel<<<64, 256, 0, stream>>>(bufA, pS2, pSS2);
    bnparams_kernel<<<1, 64, 0, stream>>>(pS2, pSS2, g2, b2, sc2, sh2, flag);

    final_kernel<<<dim3(3, 96, 2), 256, 0, stream>>>(x, bufA, sc2, sh2, d_out, flag);
}

// Round 5
// 256.003 us; speedup vs baseline: 14.5276x; 2.2130x over previous
//
#include <hip/hip_runtime.h>
#include <hip/hip_bf16.h>

#define HW 9216          // 96*96
#define NPC 18432        // per-channel element count for BN
#define NELEM 1179648    // 2*64*96*96
#define PSTRIDE 2312     // bf16 units per pos in prL: 4*72*8=2304 +8 pad (bank spread)

// ---------------------------------------------------------------------------
// DPP cross-lane adds (VALU pipe).
// ---------------------------------------------------------------------------
template <int CTRL>
__device__ __forceinline__ float dpp_add(float x) {
    int y = __builtin_amdgcn_update_dpp(0, __float_as_int(x), CTRL, 0xF, 0xF, true);
    return x + __int_as_float(y);
}
// sum over low 3 lane bits (xor 1,2,4) — all DPP
__device__ __forceinline__ float red_lo(float x) {
    x = dpp_add<0xB1>(x);    // quad_perm [1,0,3,2]
    x = dpp_add<0x4E>(x);    // quad_perm [2,3,0,1]
    x = dpp_add<0x141>(x);   // row_half_mirror
    return x;
}
// sum over high 3 lane bits (xor 8,16,32)
__device__ __forceinline__ float red_hi(float x) {
    x = dpp_add<0x128>(x);   // row_ror:8 == xor8
    x += __shfl_xor(x, 16);
    x += __shfl_xor(x, 32);
    return x;
}

// ---------------------------------------------------------------------------
// Dtype detection (bf16 vs f32 inputs), validated in R2.
// ---------------------------------------------------------------------------
__global__ void detect_kernel(const unsigned short* __restrict__ w1u,
                              int* __restrict__ flag) {
    int t = threadIdx.x;  // 64
    int bad = 0;
    for (int i = t; i < 4096; i += 64) {
        unsigned short u = (unsigned short)(w1u[i] & 0x7FFF);
        if (u >= 0x42C8) bad = 1;   // bf16 |v| >= 100.0 or NaN/Inf
    }
    unsigned long long any = __ballot(bad != 0);
    if (t == 0) *flag = (any != 0ULL) ? 1 : 0;
}

__device__ __forceinline__ float load_in(const void* p, int idx, int is32) {
    return is32 ? ((const float*)p)[idx]
                : __bfloat162float(((const __hip_bfloat16*)p)[idx]);
}

// ---------------------------------------------------------------------------
// Weight transpose: w[o][i][dy][dx][l][m] -> wT[o][j=i*9+k][m][l] (f32)
// ---------------------------------------------------------------------------
__global__ void wtrans_kernel(const void* __restrict__ w1,
                              const void* __restrict__ w2,
                              float* __restrict__ wT1, float* __restrict__ wT2,
                              const int* __restrict__ flag) {
    int is32 = *flag;
    int t = blockIdx.x * 256 + threadIdx.x;
    if (t >= 2 * 36864) return;
    const void* w = (t < 36864) ? w1 : w2;
    float* wT = (t < 36864) ? wT1 : wT2;
    int e = t % 36864;
    int l  = e & 7;
    int m  = (e >> 3) & 7;
    int k  = (e >> 6) % 9;
    int oi = e / 576;
    int dy = k / 3, dx = k % 3;
    int src = (((oi * 3 + dy) * 3 + dx) * 8 + l) * 8 + m;
    wT[e] = load_in(w, src, is32);
}

// ---------------------------------------------------------------------------
// Input transpose: x [b][c][96][96] -> xt [b][y][x][c] (f32).
// ---------------------------------------------------------------------------
__global__ void xtrans_kernel(const void* __restrict__ x, float* __restrict__ xt,
                              const int* __restrict__ flag) {
    __shared__ float tile[64 * 33];
    int is32 = *flag;
    int x0 = blockIdx.x * 32, y = blockIdx.y, b = blockIdx.z;
    for (int e = threadIdx.x; e < 2048; e += 256) {
        int xl = e & 31, c = e >> 5;
        tile[c * 33 + xl] = load_in(x, ((b * 64 + c) * 96 + y) * 96 + x0 + xl, is32);
    }
    __syncthreads();
    for (int f = threadIdx.x; f < 2048; f += 256) {
        int c = f & 63, xl = f >> 6;
        xt[((b * 96 + y) * 96 + x0 + xl) * 64 + c] = tile[c * 33 + xl];
    }
}

// ---------------------------------------------------------------------------
// Fused capsule conv + routing, LDS-priors version.
// Block = 256 = 4 waves; wave ol handles o = oh*4+ol for 8 x-positions.
// Phase 1 (lane = jj*8+m): priors -> LDS (bf16), mean-init -> LDS.
// Phase 2 (lane = p*8+i):  routing with m fully in-lane; i-reduction via DPP.
// ---------------------------------------------------------------------------
__launch_bounds__(256)
__global__ void caps_kernel(const float* __restrict__ in,     // [b][y][x][64]
                            const float* __restrict__ scale,  // layer2 BN fold
                            const float* __restrict__ shift,
                            const float* __restrict__ wT,
                            float* __restrict__ yout,         // [b][y][x][64]
                            int layer1) {
    __shared__ float patch[8 * 244];                        // [i][q=dy*10+col][l]
    __shared__ __align__(16) __hip_bfloat16 prL[8 * PSTRIDE]; // [pos][(ol*72+i*9+k)*8+m]
    __shared__ float omI[8 * 4 * 8];                        // [pos][ol][m]

    const int bx = blockIdx.x;
    const int x0 = (bx >> 1) * 8;
    const int oh = bx & 1;
    const int y  = blockIdx.y;
    const int b  = blockIdx.z;
    const int tid = threadIdx.x;

    // ---- stage patch: rows y-1..y+1, cols x0-1..x0+8, 64 channels ----
    for (int e = tid; e < 1920; e += 256) {
        int c = e & 63;          // channel fastest -> coalesced global read
        int q = e >> 6;          // 0..29 = dy*10+col
        int dy = q / 10, col = q % 10;
        int yy = y - 1 + dy, xx = x0 - 1 + col;
        float v = 0.f;
        if (yy >= 0 && yy < 96 && xx >= 0 && xx < 96) {
            v = in[((b * 96 + yy) * 96 + xx) * 64 + c];
            if (!layer1) v = v * scale[c] + shift[c];
        }
        patch[(c >> 3) * 244 + q * 8 + (c & 7)] = v;
    }
    __syncthreads();

    const int ol   = tid >> 6;     // wave -> local o
    const int lane = tid & 63;

    // ================= Phase 1: priors (lane = jj*8 + m) =================
    {
        const int m  = lane & 7;
        const int jj = lane >> 3;
        const float* wb = wT + (oh * 4 + ol) * 4608 + jj * 576 + m * 8;
        __hip_bfloat16* prw = &prL[(ol * 72 + jj * 9) * 8 + m];

        #pragma unroll
        for (int r = 0; r < 4; ++r) {       // positions 2r, 2r+1
            float s0 = 0.f, s1 = 0.f;
            #pragma unroll
            for (int t = 0; t < 9; ++t) {
                const int dy = t / 3, dx = t % 3;
                float4 w0 = *(const float4*)(wb + t * 64);
                float4 w1 = *(const float4*)(wb + t * 64 + 4);
                const float* pb = &patch[jj * 244 + (dy * 10 + dx + 2 * r) * 8];
                float4 p0 = *(const float4*)pb;
                float4 p1 = *(const float4*)(pb + 4);
                float4 q0 = *(const float4*)(pb + 8);
                float4 q1 = *(const float4*)(pb + 12);
                float a0 = p0.x * w0.x;
                a0 = fmaf(p0.y, w0.y, a0); a0 = fmaf(p0.z, w0.z, a0);
                a0 = fmaf(p0.w, w0.w, a0); a0 = fmaf(p1.x, w1.x, a0);
                a0 = fmaf(p1.y, w1.y, a0); a0 = fmaf(p1.z, w1.z, a0);
                a0 = fmaf(p1.w, w1.w, a0);
                float a1 = q0.x * w0.x;
                a1 = fmaf(q0.y, w0.y, a1); a1 = fmaf(q0.z, w0.z, a1);
                a1 = fmaf(q0.w, w0.w, a1); a1 = fmaf(q1.x, w1.x, a1);
                a1 = fmaf(q1.y, w1.y, a1); a1 = fmaf(q1.z, w1.z, a1);
                a1 = fmaf(q1.w, w1.w, a1);
                s0 += a0; s1 += a1;
                prw[(2 * r) * PSTRIDE + t * 8]     = __float2bfloat16(a0);
                prw[(2 * r + 1) * PSTRIDE + t * 8] = __float2bfloat16(a1);
            }
            s0 = red_hi(s0);
            s1 = red_hi(s1);
            if (jj == 0) {
                omI[(2 * r) * 32 + ol * 8 + m]     = s0 * (1.f / 72.f);
                omI[(2 * r + 1) * 32 + ol * 8 + m] = s1 * (1.f / 72.f);
            }
        }
    }
    // No barrier: each wave's prL/omI region is produced & consumed by itself.

    // ================= Phase 2: routing (lane = p*8 + i) =================
    const int i = lane & 7;
    const int p = lane >> 3;

    float om[8];
    {
        const float* ob = &omI[p * 32 + ol * 8];
        float4 o0 = *(const float4*)ob;
        float4 o1 = *(const float4*)(ob + 4);
        om[0] = o0.x; om[1] = o0.y; om[2] = o0.z; om[3] = o0.w;
        om[4] = o1.x; om[5] = o1.y; om[6] = o1.z; om[7] = o1.w;
    }
    float n2 = 0.f;
    #pragma unroll
    for (int mm = 0; mm < 8; ++mm) n2 = fmaf(om[mm], om[mm], n2);

    float n1[9];
    const __hip_bfloat16* pbase = &prL[p * PSTRIDE + (ol * 72 + i * 9) * 8];

    #pragma unroll
    for (int it = 0; it < 3; ++it) {
        float se = 0.f;
        float acc[8] = {0.f, 0.f, 0.f, 0.f, 0.f, 0.f, 0.f, 0.f};
        #pragma unroll
        for (int k = 0; k < 9; ++k) {
            uint4 u = *(const uint4*)(pbase + k * 8);
            float f[8];
            f[0] = __int_as_float((int)(u.x << 16));
            f[1] = __int_as_float((int)(u.x & 0xFFFF0000u));
            f[2] = __int_as_float((int)(u.y << 16));
            f[3] = __int_as_float((int)(u.y & 0xFFFF0000u));
            f[4] = __int_as_float((int)(u.z << 16));
            f[5] = __int_as_float((int)(u.z & 0xFFFF0000u));
            f[6] = __int_as_float((int)(u.w << 16));
            f[7] = __int_as_float((int)(u.w & 0xFFFF0000u));
            if (it == 0) {
                float s = 0.f;
                #pragma unroll
                for (int mm = 0; mm < 8; ++mm) s = fmaf(f[mm], f[mm], s);
                n1[k] = s;
            }
            float d = 0.f;
            #pragma unroll
            for (int mm = 0; mm < 8; ++mm) d = fmaf(f[mm], om[mm], d);
            float denom = fmaxf(n1[k] + n2 - d, 1e-8f);
            float e = __expf(d * __builtin_amdgcn_rcpf(denom));
            se += e;
            #pragma unroll
            for (int mm = 0; mm < 8; ++mm) acc[mm] = fmaf(e, f[mm], acc[mm]);
        }
        se = red_lo(se);
        #pragma unroll
        for (int mm = 0; mm < 8; ++mm) acc[mm] = red_lo(acc[mm]);
        float inv = __builtin_amdgcn_rcpf(se);
        n2 = 0.f;
        #pragma unroll
        for (int mm = 0; mm < 8; ++mm) {
            om[mm] = acc[mm] * inv;
            n2 = fmaf(om[mm], om[mm], n2);
        }
    }

    if (i == 0) {
        float* dst = &yout[((b * 96 + y) * 96 + x0 + p) * 64 + (oh * 4 + ol) * 8];
        float4 o0 = {om[0], om[1], om[2], om[3]};
        float4 o1 = {om[4], om[5], om[6], om[7]};
        *(float4*)dst = o0;
        *(float4*)(dst + 4) = o1;
    }
}

// ---------------------------------------------------------------------------
// BN stats stage 1: per-block partial sum/sumsq, coalesced over [pos][c].
// ---------------------------------------------------------------------------
__global__ void stats_kernel(const float* __restrict__ yt,
                             float* __restrict__ pS, float* __restrict__ pSS) {
    const int c = threadIdx.x & 63, sub = threadIdx.x >> 6;
    const int base = blockIdx.x * 288;
    float s = 0.f, ss = 0.f;
    for (int r = 0; r < 72; ++r) {
        float v = yt[(base + r * 4 + sub) * 64 + c];
        s += v;
        ss = fmaf(v, v, ss);
    }
    __shared__ float ls[4][64], lss[4][64];
    ls[sub][c] = s;
    lss[sub][c] = ss;
    __syncthreads();
    if (threadIdx.x < 64) {
        int cc = threadIdx.x;
        pS[blockIdx.x * 64 + cc]  = ls[0][cc] + ls[1][cc] + ls[2][cc] + ls[3][cc];
        pSS[blockIdx.x * 64 + cc] = lss[0][cc] + lss[1][cc] + lss[2][cc] + lss[3][cc];
    }
}

// ---------------------------------------------------------------------------
// BN stats stage 2: reduce partials per channel, fold gamma/beta.
// ---------------------------------------------------------------------------
__global__ void bnparams_kernel(const float* __restrict__ pS, const float* __restrict__ pSS,
                                const void* __restrict__ gamma,
                                const void* __restrict__ beta,
                                float* __restrict__ sc, float* __restrict__ sh,
                                const int* __restrict__ flag) {
    int is32 = *flag;
    int c = threadIdx.x;  // 64
    float s = 0.f, ss = 0.f;
    for (int k = 0; k < 64; ++k) { s += pS[k * 64 + c]; ss += pSS[k * 64 + c]; }
    float mean = s * (1.f / (float)NPC);
    float var  = fmaxf(ss * (1.f / (float)NPC) - mean * mean, 0.f);
    float inv  = rsqrtf(var + 1e-5f);
    float g = load_in(gamma, c, is32) * inv;
    sc[c] = g;
    sh[c] = load_in(beta, c, is32) - mean * g;
}

// ---------------------------------------------------------------------------
// Final: out[b][c][y][x] = x + bn2(y2), tiled transpose from [pos][c].
// ---------------------------------------------------------------------------
__global__ void final_kernel(const void* __restrict__ xin,
                             const float* __restrict__ yt2,
                             const float* __restrict__ sc, const float* __restrict__ sh,
                             void* __restrict__ outp,
                             const int* __restrict__ flag) {
    __shared__ float tile[64 * 33];
    int is32 = *flag;
    int x0 = blockIdx.x * 32, y = blockIdx.y, b = blockIdx.z;
    for (int e = threadIdx.x; e < 2048; e += 256) {
        int c = e & 63, xl = e >> 6;
        float v = yt2[((b * 96 + y) * 96 + x0 + xl) * 64 + c];
        tile[c * 33 + xl] = v * sc[c] + sh[c];
    }
    __syncthreads();
    for (int f = threadIdx.x; f < 2048; f += 256) {
        int xl = f & 31, c = f >> 5;
        int idx = ((b * 64 + c) * 96 + y) * 96 + x0 + xl;
        float v = load_in(xin, idx, is32) + tile[c * 33 + xl];
        if (is32) ((float*)outp)[idx] = v;
        else      ((__hip_bfloat16*)outp)[idx] = __float2bfloat16(v);
    }
}

// ---------------------------------------------------------------------------
extern "C" void kernel_launch(void* const* d_in, const int* in_sizes, int n_in,
                              void* d_out, int out_size, void* d_ws, size_t ws_size,
                              hipStream_t stream) {
    const void* x  = d_in[0];
    const void* w1 = d_in[1];
    const void* g1 = d_in[2];
    const void* b1 = d_in[3];
    const void* w2 = d_in[4];
    const void* g2 = d_in[5];
    const void* b2 = d_in[6];

    float* ws   = (float*)d_ws;
    float* bufA = ws;                  // xt (layer1 input) / yt2 (alias; xt dead by caps2)
    float* bufB = bufA + NELEM;        // yt1
    float* wT1  = bufB + NELEM;        // 36864
    float* wT2  = wT1 + 36864;         // 36864
    float* pS1  = wT2 + 36864;         // 4096
    float* pSS1 = pS1 + 4096;
    float* pS2  = pSS1 + 4096;
    float* pSS2 = pS2 + 4096;
    float* sc1  = pSS2 + 4096;
    float* sh1  = sc1 + 64;
    float* sc2  = sh1 + 64;
    float* sh2  = sc2 + 64;
    int*  flag  = (int*)(sh2 + 64);

    detect_kernel<<<1, 64, 0, stream>>>((const unsigned short*)w1, flag);
    wtrans_kernel<<<288, 256, 0, stream>>>(w1, w2, wT1, wT2, flag);
    xtrans_kernel<<<dim3(3, 96, 2), 256, 0, stream>>>(x, bufA, flag);

    dim3 cgrid(24, 96, 2);   // (x-group of 8) x (o-half), rows, batch
    caps_kernel<<<cgrid, 256, 0, stream>>>(bufA, sc1, sh1, wT1, bufB, 1);
    stats_kernel<<<64, 256, 0, stream>>>(bufB, pS1, pSS1);
    bnparams_kernel<<<1, 64, 0, stream>>>(pS1, pSS1, g1, b1, sc1, sh1, flag);

    caps_kernel<<<cgrid, 256, 0, stream>>>(bufB, sc1, sh1, wT2, bufA, 0);
    stats_kernel<<<64, 256, 0, stream>>>(bufA, pS2, pSS2);
    bnparams_kernel<<<1, 64, 0, stream>>>(pS2, pSS2, g2, b2, sc2, sh2, flag);

    final_kernel<<<dim3(3, 96, 2), 256, 0, stream>>>(x, bufA, sc2, sh2, d_out, flag);
}

// Round 6
// 213.658 us; speedup vs baseline: 17.4068x; 1.1982x over previous
//
#include <hip/hip_runtime.h>
#include <hip/hip_bf16.h>

#define HW 9216          // 96*96
#define NPC 18432        // per-channel element count for BN
#define NELEM 1179648    // 2*64*96*96
#define PSTRIDE 2312     // bf16 units per pos in prL: 4*72*8=2304 +8 pad

typedef __attribute__((ext_vector_type(2))) float f32x2;

__device__ __forceinline__ f32x2 fma2(f32x2 a, f32x2 b, f32x2 c) {
#if __has_builtin(__builtin_elementwise_fma)
    return __builtin_elementwise_fma(a, b, c);
#else
    return f32x2{fmaf(a.x, b.x, c.x), fmaf(a.y, b.y, c.y)};
#endif
}
// dot of 8 floats held as 4 f32x2 pairs -> scalar (v_pk_fma_f32 eligible)
__device__ __forceinline__ float dot8v(f32x2 a0, f32x2 a1, f32x2 a2, f32x2 a3,
                                       f32x2 b0, f32x2 b1, f32x2 b2, f32x2 b3) {
    f32x2 acc = a0 * b0;
    acc = fma2(a1, b1, acc);
    acc = fma2(a2, b2, acc);
    acc = fma2(a3, b3, acc);
    return acc.x + acc.y;
}

// ---------------------------------------------------------------------------
// DPP cross-lane adds (VALU pipe).
// ---------------------------------------------------------------------------
template <int CTRL>
__device__ __forceinline__ float dpp_add(float x) {
    int y = __builtin_amdgcn_update_dpp(0, __float_as_int(x), CTRL, 0xF, 0xF, true);
    return x + __int_as_float(y);
}
__device__ __forceinline__ float red_lo(float x) {   // xor 1,2,4
    x = dpp_add<0xB1>(x);
    x = dpp_add<0x4E>(x);
    x = dpp_add<0x141>(x);
    return x;
}
__device__ __forceinline__ float red_hi(float x) {   // xor 8,16,32
    x = dpp_add<0x128>(x);
    x += __shfl_xor(x, 16);
    x += __shfl_xor(x, 32);
    return x;
}

// ---------------------------------------------------------------------------
// Per-wave dtype detection from w1's first 4096 u16 words (validated R2).
// ---------------------------------------------------------------------------
__device__ __forceinline__ int detect_is32(const unsigned short* __restrict__ w1u) {
    int lane = threadIdx.x & 63;
    int bad = 0;
    #pragma unroll
    for (int i = 0; i < 16; ++i) {
        unsigned short u = (unsigned short)(w1u[lane + i * 64] & 0x7FFF);
        bad |= (u >= 0x42C8);   // bf16 |v| >= 100 or NaN/Inf
    }
    return (__ballot(bad) != 0ULL) ? 1 : 0;
}

__device__ __forceinline__ float load_in(const void* p, int idx, int is32) {
    return is32 ? ((const float*)p)[idx]
                : __bfloat162float(((const __hip_bfloat16*)p)[idx]);
}

__device__ __forceinline__ float lo16(unsigned v) { return __int_as_float((int)(v << 16)); }
__device__ __forceinline__ float hi16(unsigned v) { return __int_as_float((int)(v & 0xFFFF0000u)); }

// ---------------------------------------------------------------------------
// prep: blocks 0..575 = x transpose to [b][y][x][c]; 576..863 = weight
// transpose to wT[o][j][m][l]; 864 = zero BN-stat accumulators.
// ---------------------------------------------------------------------------
__launch_bounds__(256)
__global__ void prep_kernel(const void* __restrict__ x,
                            const void* __restrict__ w1, const void* __restrict__ w2,
                            float* __restrict__ xt,
                            float* __restrict__ wT1, float* __restrict__ wT2,
                            float* __restrict__ statz) {
    __shared__ float tile[64 * 33];
    const int is32 = detect_is32((const unsigned short*)w1);
    const int bid = blockIdx.x;
    if (bid < 576) {
        int xb = bid % 3, y = (bid / 3) % 96, b = bid / 288;
        int x0 = xb * 32;
        for (int e = threadIdx.x; e < 2048; e += 256) {
            int xl = e & 31, c = e >> 5;
            tile[c * 33 + xl] = load_in(x, ((b * 64 + c) * 96 + y) * 96 + x0 + xl, is32);
        }
        __syncthreads();
        for (int f = threadIdx.x; f < 2048; f += 256) {
            int c = f & 63, xl = f >> 6;
            xt[((b * 96 + y) * 96 + x0 + xl) * 64 + c] = tile[c * 33 + xl];
        }
    } else if (bid < 864) {
        int t = (bid - 576) * 256 + threadIdx.x;   // 0..73727
        const void* w = (t < 36864) ? w1 : w2;
        float* wT = (t < 36864) ? wT1 : wT2;
        int e = t % 36864;
        int l  = e & 7;
        int m  = (e >> 3) & 7;
        int k  = (e >> 6) % 9;
        int oi = e / 576;
        int dy = k / 3, dx = k % 3;
        int src = (((oi * 3 + dy) * 3 + dx) * 8 + l) * 8 + m;
        wT[e] = load_in(w, src, is32);
    } else {
        for (int e = threadIdx.x; e < 2048; e += 256) statz[e] = 0.f;
    }
}

// ---------------------------------------------------------------------------
// Fused capsule conv + routing + BN-stat partials.
// Block = 256 = 4 waves; wave ol handles o = oh*4+ol for 8 x-positions.
// Phase 1 (lane = jj*8+m): register-cached patch rows -> priors -> LDS bf16.
// Phase 2 (lane = p*8+i):  register-cached priors, m in-lane, DPP i-reduce.
// Epilogue: block-local channel sums -> spread atomicAdd into statL.
// ---------------------------------------------------------------------------
__launch_bounds__(256, 3)
__global__ void caps_kernel(const float* __restrict__ in,     // [b][y][x][64]
                            const float* __restrict__ scale,  // layer2 BN fold
                            const float* __restrict__ shift,
                            const float* __restrict__ wT,
                            float* __restrict__ yout,         // [b][y][x][64]
                            float* __restrict__ statL,        // [8 copies][128]
                            int layer1) {
    __shared__ float patch[8 * 244];                          // [i][q=dy*10+col][l]
    __shared__ __align__(16) __hip_bfloat16 prL[8 * PSTRIDE]; // [pos][(ol*72+i*9+k)*8+m]
    __shared__ float omI[8 * 32];                             // [pos][ol*8+m]

    const int bx = blockIdx.x;
    const int x0 = (bx >> 1) * 8;
    const int oh = bx & 1;
    const int y  = blockIdx.y;
    const int b  = blockIdx.z;
    const int tid = threadIdx.x;

    // ---- stage patch: rows y-1..y+1, cols x0-1..x0+8, 64 channels ----
    for (int e = tid; e < 1920; e += 256) {
        int c = e & 63;
        int q = e >> 6;          // 0..29 = dy*10+col
        int dy = q / 10, col = q % 10;
        int yy = y - 1 + dy, xx = x0 - 1 + col;
        float v = 0.f;
        if (yy >= 0 && yy < 96 && xx >= 0 && xx < 96) {
            v = in[((b * 96 + yy) * 96 + xx) * 64 + c];
            if (!layer1) v = v * scale[c] + shift[c];
        }
        patch[(c >> 3) * 244 + q * 8 + (c & 7)] = v;
    }
    __syncthreads();

    const int ol   = tid >> 6;
    const int lane = tid & 63;

    // ================= Phase 1: priors (lane = jj*8 + m) =================
    {
        const int m  = lane & 7;
        const int jj = lane >> 3;
        const float* wb = wT + (oh * 4 + ol) * 4608 + jj * 576 + m * 8;
        __hip_bfloat16* prw = &prL[(ol * 72 + jj * 9) * 8 + m];

        float s[8] = {0.f, 0.f, 0.f, 0.f, 0.f, 0.f, 0.f, 0.f};
        #pragma unroll
        for (int dy = 0; dy < 3; ++dy) {
            f32x2 row2[40];   // the full 10-col row for this (jj,dy): 80 floats
            const float4* rb = (const float4*)&patch[jj * 244 + dy * 80];
            #pragma unroll
            for (int v = 0; v < 20; ++v) {
                float4 tt = rb[v];
                row2[2 * v]     = f32x2{tt.x, tt.y};
                row2[2 * v + 1] = f32x2{tt.z, tt.w};
            }
            #pragma unroll
            for (int dx = 0; dx < 3; ++dx) {
                const int t = dy * 3 + dx;
                float4 wa = *(const float4*)(wb + t * 64);
                float4 wc = *(const float4*)(wb + t * 64 + 4);
                f32x2 w0{wa.x, wa.y}, w1v{wa.z, wa.w}, w2v{wc.x, wc.y}, w3v{wc.z, wc.w};
                #pragma unroll
                for (int p = 0; p < 8; ++p) {
                    const int base = (dx + p) * 4;
                    float a = dot8v(row2[base], row2[base + 1], row2[base + 2], row2[base + 3],
                                    w0, w1v, w2v, w3v);
                    s[p] += a;
                    prw[p * PSTRIDE + t * 8] = __float2bfloat16(a);
                }
            }
        }
        #pragma unroll
        for (int p = 0; p < 8; ++p) {
            float v = red_hi(s[p]);
            if (jj == 0) omI[p * 32 + ol * 8 + m] = v * (1.f / 72.f);
        }
    }
    // No barrier: each wave's prL/omI region is produced & consumed by itself.

    // ================= Phase 2: routing (lane = p*8 + i) =================
    const int i = lane & 7;
    const int p = lane >> 3;
    const __hip_bfloat16* pbase = &prL[p * PSTRIDE + (ol * 72 + i * 9) * 8];

    uint4 u[9];
    #pragma unroll
    for (int k = 0; k < 9; ++k) u[k] = *(const uint4*)(pbase + k * 8);

    f32x2 fr[36];
    float n1[9];
    #pragma unroll
    for (int k = 0; k < 9; ++k) {
        fr[4 * k + 0] = f32x2{lo16(u[k].x), hi16(u[k].x)};
        fr[4 * k + 1] = f32x2{lo16(u[k].y), hi16(u[k].y)};
        fr[4 * k + 2] = f32x2{lo16(u[k].z), hi16(u[k].z)};
        fr[4 * k + 3] = f32x2{lo16(u[k].w), hi16(u[k].w)};
        n1[k] = dot8v(fr[4 * k], fr[4 * k + 1], fr[4 * k + 2], fr[4 * k + 3],
                      fr[4 * k], fr[4 * k + 1], fr[4 * k + 2], fr[4 * k + 3]);
    }

    f32x2 om2[4];
    {
        const float* ob = &omI[p * 32 + ol * 8];
        float4 o0 = *(const float4*)ob;
        float4 o1 = *(const float4*)(ob + 4);
        om2[0] = f32x2{o0.x, o0.y}; om2[1] = f32x2{o0.z, o0.w};
        om2[2] = f32x2{o1.x, o1.y}; om2[3] = f32x2{o1.z, o1.w};
    }
    float n2 = dot8v(om2[0], om2[1], om2[2], om2[3], om2[0], om2[1], om2[2], om2[3]);

    #pragma unroll
    for (int it = 0; it < 3; ++it) {
        float se = 0.f;
        f32x2 acc2[4] = {f32x2{0.f, 0.f}, f32x2{0.f, 0.f}, f32x2{0.f, 0.f}, f32x2{0.f, 0.f}};
        #pragma unroll
        for (int k = 0; k < 9; ++k) {
            float d = dot8v(fr[4 * k], fr[4 * k + 1], fr[4 * k + 2], fr[4 * k + 3],
                            om2[0], om2[1], om2[2], om2[3]);
            float denom = fmaxf(n1[k] + n2 - d, 1e-8f);
            float e = __expf(d * __builtin_amdgcn_rcpf(denom));
            se += e;
            f32x2 ev{e, e};
            acc2[0] = fma2(ev, fr[4 * k + 0], acc2[0]);
            acc2[1] = fma2(ev, fr[4 * k + 1], acc2[1]);
            acc2[2] = fma2(ev, fr[4 * k + 2], acc2[2]);
            acc2[3] = fma2(ev, fr[4 * k + 3], acc2[3]);
        }
        se = red_lo(se);
        #pragma unroll
        for (int q = 0; q < 4; ++q) {
            acc2[q].x = red_lo(acc2[q].x);
            acc2[q].y = red_lo(acc2[q].y);
        }
        float inv = __builtin_amdgcn_rcpf(se);
        f32x2 iv{inv, inv};
        #pragma unroll
        for (int q = 0; q < 4; ++q) om2[q] = acc2[q] * iv;
        n2 = dot8v(om2[0], om2[1], om2[2], om2[3], om2[0], om2[1], om2[2], om2[3]);
    }

    if (i == 0) {
        float4 o0 = {om2[0].x, om2[0].y, om2[1].x, om2[1].y};
        float4 o1 = {om2[2].x, om2[2].y, om2[3].x, om2[3].y};
        float* dst = &yout[((b * 96 + y) * 96 + x0 + p) * 64 + (oh * 4 + ol) * 8];
        *(float4*)dst = o0;
        *(float4*)(dst + 4) = o1;
        // park for BN-stat reduction
        *(float4*)&omI[p * 32 + ol * 8] = o0;
        *(float4*)&omI[p * 32 + ol * 8 + 4] = o1;
    }
    __syncthreads();

    // ---- BN stat partials: 32 channels (oh half), sum over 8 positions ----
    if (tid < 64) {
        int c32 = tid & 31, sel = tid >> 5;
        float v = 0.f;
        #pragma unroll
        for (int pp = 0; pp < 8; ++pp) {
            float uu = omI[pp * 32 + c32];
            v += sel ? uu * uu : uu;
        }
        int cp = (blockIdx.x + blockIdx.y * 3 + blockIdx.z) & 7;
        atomicAdd(&statL[cp * 128 + sel * 64 + oh * 32 + c32], v);
    }
}

// ---------------------------------------------------------------------------
// Reduce the 8 stat copies per channel, fold gamma/beta.
// ---------------------------------------------------------------------------
__global__ void bnparams_kernel(const float* __restrict__ statL,
                                const void* __restrict__ gamma,
                                const void* __restrict__ beta,
                                const void* __restrict__ w1,
                                float* __restrict__ sc, float* __restrict__ sh) {
    int is32 = detect_is32((const unsigned short*)w1);
    int c = threadIdx.x;  // 64
    float s = 0.f, ss = 0.f;
    #pragma unroll
    for (int cp = 0; cp < 8; ++cp) {
        s  += statL[cp * 128 + c];
        ss += statL[cp * 128 + 64 + c];
    }
    float mean = s * (1.f / (float)NPC);
    float var  = fmaxf(ss * (1.f / (float)NPC) - mean * mean, 0.f);
    float inv  = rsqrtf(var + 1e-5f);
    float g = load_in(gamma, c, is32) * inv;
    sc[c] = g;
    sh[c] = load_in(beta, c, is32) - mean * g;
}

// ---------------------------------------------------------------------------
// Final: out[b][c][y][x] = x + bn2(y2), tiled transpose from [pos][c].
// ---------------------------------------------------------------------------
__launch_bounds__(256)
__global__ void final_kernel(const void* __restrict__ xin,
                             const float* __restrict__ yt2,
                             const float* __restrict__ sc, const float* __restrict__ sh,
                             const void* __restrict__ w1,
                             void* __restrict__ outp) {
    __shared__ float tile[64 * 33];
    int is32 = detect_is32((const unsigned short*)w1);
    int x0 = blockIdx.x * 32, y = blockIdx.y, b = blockIdx.z;
    for (int e = threadIdx.x; e < 2048; e += 256) {
        int c = e & 63, xl = e >> 6;
        float v = yt2[((b * 96 + y) * 96 + x0 + xl) * 64 + c];
        tile[c * 33 + xl] = v * sc[c] + sh[c];
    }
    __syncthreads();
    for (int f = threadIdx.x; f < 2048; f += 256) {
        int xl = f & 31, c = f >> 5;
        int idx = ((b * 64 + c) * 96 + y) * 96 + x0 + xl;
        float v = load_in(xin, idx, is32) + tile[c * 33 + xl];
        if (is32) ((float*)outp)[idx] = v;
        else      ((__hip_bfloat16*)outp)[idx] = __float2bfloat16(v);
    }
}

// ---------------------------------------------------------------------------
extern "C" void kernel_launch(void* const* d_in, const int* in_sizes, int n_in,
                              void* d_out, int out_size, void* d_ws, size_t ws_size,
                              hipStream_t stream) {
    const void* x  = d_in[0];
    const void* w1 = d_in[1];
    const void* g1 = d_in[2];
    const void* b1 = d_in[3];
    const void* w2 = d_in[4];
    const void* g2 = d_in[5];
    const void* b2 = d_in[6];

    float* ws   = (float*)d_ws;
    float* bufA = ws;                  // xt (layer1 input) / yt2 (alias; xt dead by caps2)
    float* bufB = bufA + NELEM;        // yt1
    float* wT1  = bufB + NELEM;        // 36864
    float* wT2  = wT1 + 36864;         // 36864
    float* statz = wT2 + 36864;        // 2048 (2 layers x 8 copies x 128)
    float* statL1 = statz;
    float* statL2 = statz + 1024;
    float* sc1  = statz + 2048;
    float* sh1  = sc1 + 64;
    float* sc2  = sh1 + 64;
    float* sh2  = sc2 + 64;

    prep_kernel<<<865, 256, 0, stream>>>(x, w1, w2, bufA, wT1, wT2, statz);

    dim3 cgrid(24, 96, 2);   // (x-group of 8) x (o-half), rows, batch
    caps_kernel<<<cgrid, 256, 0, stream>>>(bufA, nullptr, nullptr, wT1, bufB, statL1, 1);
    bnparams_kernel<<<1, 64, 0, stream>>>(statL1, g1, b1, w1, sc1, sh1);

    caps_kernel<<<cgrid, 256, 0, stream>>>(bufB, sc1, sh1, wT2, bufA, statL2, 0);
    bnparams_kernel<<<1, 64, 0, stream>>>(statL2, g2, b2, w1, sc2, sh2);

    final_kernel<<<dim3(3, 96, 2), 256, 0, stream>>>(x, bufA, sc2, sh2, w1, d_out);
}